// Round 1
// baseline (191.528 us; speedup 1.0000x reference)
//
#include <hip/hip_runtime.h>
#include <math.h>

// Problem constants
#define B_ 64
#define N_ 128
#define D_ 128
#define BN_ 8192            // B_*N_
#define NG_ 50
#define CUTOFF_ 10.0f

// ---------------------------------------------------------------------------
// 1. RMSNorm: x1[row][d] = x * rsqrt(mean(x^2)+eps) * w
// grid 8192 blocks x 128 threads
__global__ __launch_bounds__(128) void rms_k(const float* __restrict__ x,
                                             const float* __restrict__ w,
                                             float* __restrict__ x1) {
    int row = blockIdx.x;
    int d = threadIdx.x;
    float v = x[(size_t)row * D_ + d];
    float s = v * v;
    #pragma unroll
    for (int o = 32; o > 0; o >>= 1) s += __shfl_down(s, o, 64);
    __shared__ float acc2[2];
    if ((d & 63) == 0) acc2[d >> 6] = s;
    __syncthreads();
    float tot = acc2[0] + acc2[1];
    float r = rsqrtf(tot * (1.0f / D_) + 1e-5f);
    x1[(size_t)row * D_ + d] = v * r * w[d];
}

// ---------------------------------------------------------------------------
// 2. passthrough copy: pos (24576 floats) and map_idx (8192 ints -> float)
__global__ __launch_bounds__(256) void copy_k(const float* __restrict__ pos,
                                              const int* __restrict__ mi,
                                              float* __restrict__ out) {
    int i = blockIdx.x * 256 + threadIdx.x;
    if (i < BN_ * 3) out[(size_t)BN_ * D_ + i] = pos[i];
    if (i < BN_) out[(size_t)BN_ * D_ + BN_ * 3 + i] = (float)mi[i];
}

// ---------------------------------------------------------------------------
// 3. adjacency: dist, edge mask bits, smeared adj
// grid (16 row-tiles, 64 batches) x 256 threads; each block: 8 rows x 128 cols
__global__ __launch_bounds__(256) void adj_k(const float* __restrict__ pos,
                                             const float* __restrict__ lin_w,
                                             const float* __restrict__ lin_b,
                                             float* __restrict__ adj,
                                             unsigned long long* __restrict__ em) {
    __shared__ float px[N_], py[N_], pz[N_];
    __shared__ float lw[NG_];
    int b = blockIdx.y;
    int tid = threadIdx.x;
    if (tid < N_) {
        const float* p = pos + (size_t)(b * N_ + tid) * 3;
        px[tid] = p[0]; py[tid] = p[1]; pz[tid] = p[2];
    } else if (tid - N_ < NG_) {
        lw[tid - N_] = lin_w[tid - N_];
    }
    __syncthreads();
    float linb = lin_b[0];
    int j = tid & 127;
    int il = tid >> 7;          // 0..1
    int wid = tid >> 6;         // wave id 0..3; (wid&1) = j half
    const float DEL = 10.0f / 49.0f;
    const float COEFF = -0.5f / (DEL * DEL);
    #pragma unroll
    for (int p = 0; p < 4; p++) {
        int i = blockIdx.x * 8 + p * 2 + il;
        float dx = px[i] - px[j], dy = py[i] - py[j], dz = pz[i] - pz[j];
        float d2 = dx * dx + dy * dy + dz * dz;
        float dist = (i == j) ? 1.0f : sqrtf(d2);
        bool edge = (i != j) && (dist < CUTOFF_);
        float val = 0.0f;
        if (edge) {
            int g0 = (int)ceilf((dist - 1.75f) / DEL); if (g0 < 0) g0 = 0;
            int g1 = (int)floorf((dist + 1.75f) / DEL); if (g1 > NG_ - 1) g1 = NG_ - 1;
            float s = linb;
            for (int g = g0; g <= g1; g++) {
                float t = dist - (float)g * DEL;
                s += lw[g] * expf(COEFF * t * t);
            }
            val = s;
        }
        adj[((size_t)b * N_ + i) * N_ + j] = val;
        unsigned long long msk = __ballot(edge);
        if ((tid & 63) == 0) em[((size_t)b * N_ + i) * 2 + (wid & 1)] = msk;
    }
}

// ---------------------------------------------------------------------------
// Generic fp32 GEMM: C[M x ncols] = A[M x 128] @ W[128 x ncols] (+ epilogue)
// block tile 32 rows x 128 cols, thread tile 4x4, 256 threads.
// EPI: 0 = none, 1 = bias+relu, 2 = bias, 3 = isfinite-clean + add X1 (residual)
// wbs: per-batch W stride (elements) for batched weight (0 = shared W)
template <int EPI>
__global__ __launch_bounds__(256) void gemm_k(const float* __restrict__ A,
                                              const float* __restrict__ W,
                                              const float* __restrict__ bias,
                                              float* __restrict__ C,
                                              const float* __restrict__ X1,
                                              int wstride, int cstride, int wbs) {
    extern __shared__ float sm[];
    float* As = sm;              // 32*128
    float* Ws = sm + 32 * 128;   // 128*128
    int tid = threadIdx.x;
    int row_base = blockIdx.x * 32;
    int col_base = blockIdx.y * 128;

    // stage A tile (contiguous 4096 floats)
    const float4* Ag = reinterpret_cast<const float4*>(A + (size_t)row_base * 128);
    float4* As4 = reinterpret_cast<float4*>(As);
    #pragma unroll
    for (int i = 0; i < 4; i++) As4[tid + i * 256] = Ag[tid + i * 256];

    // stage W tile (128 rows x 128 cols)
    const float* Wp = W + (size_t)(row_base >> 7) * wbs;
    float4* Ws4 = reinterpret_cast<float4*>(Ws);
    #pragma unroll
    for (int i = 0; i < 16; i++) {
        int q = tid + i * 256;
        int r = q >> 5, cv = q & 31;
        Ws4[q] = *reinterpret_cast<const float4*>(Wp + (size_t)r * wstride + col_base + cv * 4);
    }
    __syncthreads();

    int ct = tid & 31, rt = tid >> 5;
    int c0 = ct * 4, r0 = rt * 4;
    float acc[4][4] = {};
    #pragma unroll 4
    for (int kb = 0; kb < 32; kb++) {
        float af[4][4], wf[4][4];
        #pragma unroll
        for (int i = 0; i < 4; i++) {
            float4 t = As4[(r0 + i) * 32 + kb];
            af[i][0] = t.x; af[i][1] = t.y; af[i][2] = t.z; af[i][3] = t.w;
        }
        #pragma unroll
        for (int kk = 0; kk < 4; kk++) {
            float4 t = Ws4[(kb * 4 + kk) * 32 + ct];
            wf[kk][0] = t.x; wf[kk][1] = t.y; wf[kk][2] = t.z; wf[kk][3] = t.w;
        }
        #pragma unroll
        for (int kk = 0; kk < 4; kk++)
            #pragma unroll
            for (int i = 0; i < 4; i++)
                #pragma unroll
                for (int jj = 0; jj < 4; jj++)
                    acc[i][jj] = fmaf(af[i][kk], wf[kk][jj], acc[i][jj]);
    }

    #pragma unroll
    for (int i = 0; i < 4; i++) {
        int row = row_base + r0 + i;
        int col = col_base + c0;
        float v[4];
        #pragma unroll
        for (int jj = 0; jj < 4; jj++) {
            float t = acc[i][jj];
            if (EPI == 1) { t += bias[col + jj]; t = fmaxf(t, 0.0f); }
            if (EPI == 2) { t += bias[col + jj]; }
            if (EPI == 3) {
                t = isfinite(t) ? t : 0.0f;
                t += X1[(size_t)row * 128 + col + jj];
            }
            v[jj] = t;
        }
        float4 o = make_float4(v[0], v[1], v[2], v[3]);
        *reinterpret_cast<float4*>(C + (size_t)row * cstride + col) = o;
    }
}

// ---------------------------------------------------------------------------
// 5. aggregation: agg[b][i][c] = (sum_{j in mask(i)} h[b][j][c]) / max(deg,1)
// grid (4 row-tiles, 64 batches) x 256 threads; stages h[b] (64KB) in LDS
__global__ __launch_bounds__(256) void agg_k(const float* __restrict__ h,
                                             const unsigned long long* __restrict__ em,
                                             float* __restrict__ agg) {
    extern __shared__ float hs[];    // 128*128
    int b = blockIdx.y;
    int tid = threadIdx.x;
    const float4* hg = reinterpret_cast<const float4*>(h + (size_t)b * N_ * D_);
    float4* hs4 = reinterpret_cast<float4*>(hs);
    #pragma unroll
    for (int i = 0; i < 16; i++) hs4[tid + i * 256] = hg[tid + i * 256];
    __syncthreads();
    int c = tid & 127, il = tid >> 7;
    int row_base = blockIdx.x * 32;
    for (int p = 0; p < 16; p++) {
        int i = row_base + p * 2 + il;
        unsigned long long b0 = em[((size_t)b * N_ + i) * 2];
        unsigned long long b1 = em[((size_t)b * N_ + i) * 2 + 1];
        int cnt = __popcll(b0) + __popcll(b1);
        float accv = 0.0f;
        unsigned long long m = b0;
        while (m) { int j = __builtin_ctzll(m); m &= m - 1; accv += hs[j * D_ + c]; }
        m = b1;
        while (m) { int j = __builtin_ctzll(m); m &= m - 1; accv += hs[(j + 64) * D_ + c]; }
        float deg = (cnt > 0) ? (float)cnt : 1.0f;
        agg[((size_t)b * N_ + i) * D_ + c] = accv / deg;
    }
}

// ---------------------------------------------------------------------------
// 8. fused conv1d + silu + x_proj + dt_proj + softplus, per (b,t) row
// grid 8192 x 128 threads (thread = channel d)
__global__ __launch_bounds__(128) void convsm_k(const float* __restrict__ xr,
                                                const float* __restrict__ conv_w,
                                                const float* __restrict__ conv_b,
                                                const float* __restrict__ xpw,
                                                const float* __restrict__ dtw,
                                                const float* __restrict__ dtb,
                                                float* __restrict__ xc,
                                                float* __restrict__ bc,
                                                float* __restrict__ delta) {
    int row = blockIdx.x;
    int bt = row & 127;
    int d = threadIdx.x;
    float accv = conv_b[d];
    #pragma unroll
    for (int jj = 0; jj < 4; jj++) {
        int tt = bt + jj - 3;
        if (tt >= 0) accv = fmaf(xr[((size_t)(row + jj - 3)) * 256 + d], conv_w[d * 4 + jj], accv);
    }
    float xcv = accv / (1.0f + expf(-accv));   // silu
    xc[(size_t)row * D_ + d] = xcv;
    __shared__ float xs[D_];
    __shared__ float dbl[12];
    xs[d] = xcv;
    __syncthreads();
    if (d < 12) {
        float s = 0.0f;
        for (int k = 0; k < D_; k++) s = fmaf(xs[k], xpw[k * 12 + d], s);
        dbl[d] = s;
        if (d >= 8) bc[(size_t)row * 4 + (d - 8)] = s;
    }
    __syncthreads();
    float s = dtb[d];
    #pragma unroll
    for (int r = 0; r < 8; r++) s = fmaf(dbl[r], dtw[r * D_ + d], s);
    float sp = fmaxf(s, 0.0f) + log1pf(expf(-fabsf(s)));  // softplus
    delta[(size_t)row * D_ + d] = sp;
}

// ---------------------------------------------------------------------------
// 10. selective scan: one thread per (b,d), sequential over t=0..127
// yfull = (y + xc*D_param) * silu(res)
__global__ __launch_bounds__(256) void scan_k(const float* __restrict__ dp_,
                                              const float* __restrict__ xc,
                                              const float* __restrict__ bc,
                                              const float* __restrict__ xr,
                                              const float* __restrict__ A_log,
                                              const float* __restrict__ Dpar,
                                              float* __restrict__ yfull) {
    int g = blockIdx.x * 256 + threadIdx.x;
    int b = g >> 7, d = g & 127;
    float a1 = -expf(A_log[d * 2]);
    float a2 = -expf(A_log[d * 2 + 1]);
    float Dp = Dpar[d];
    float h1 = 0.0f, h2 = 0.0f;
    size_t base = (size_t)b * N_;
    for (int t = 0; t < N_; t++) {
        size_t row = base + t;
        float dpv = dp_[row * D_ + d];
        float xcv = xc[row * D_ + d];
        float bm0 = bc[row * 4 + 0], bm1 = bc[row * 4 + 1];
        float cm0 = bc[row * 4 + 2], cm1 = bc[row * 4 + 3];
        float e1 = expf(dpv * a1), e2 = expf(dpv * a2);
        float bu = dpv * xcv;
        h1 = fmaf(e1, h1, bu * bm0);
        h2 = fmaf(e2, h2, bu * bm1);
        float y = fmaf(h1, cm0, h2 * cm1);
        float r = xr[row * 256 + 128 + d];
        float yv = fmaf(xcv, Dp, y) * (r / (1.0f + expf(-r)));
        yfull[row * D_ + d] = yv;
    }
}

// ---------------------------------------------------------------------------
extern "C" void kernel_launch(void* const* d_in, const int* in_sizes, int n_in,
                              void* d_out, int out_size, void* d_ws, size_t ws_size,
                              hipStream_t stream) {
    const float* x        = (const float*)d_in[0];
    const float* pos      = (const float*)d_in[1];
    const int*   mi       = (const int*)d_in[2];
    // d_in[3] = batch (unused)
    const float* norm_w   = (const float*)d_in[4];
    const float* w1       = (const float*)d_in[5];
    const float* b1       = (const float*)d_in[6];
    const float* w2       = (const float*)d_in[7];
    const float* b2       = (const float*)d_in[8];
    const float* lin_w    = (const float*)d_in[9];
    const float* lin_b    = (const float*)d_in[10];
    const float* in_proj  = (const float*)d_in[11];
    const float* conv_w   = (const float*)d_in[12];
    const float* conv_b   = (const float*)d_in[13];
    const float* xpw      = (const float*)d_in[14];
    const float* dtw      = (const float*)d_in[15];
    const float* dtb      = (const float*)d_in[16];
    const float* A_log    = (const float*)d_in[17];
    const float* Dpar     = (const float*)d_in[18];
    const float* out_proj = (const float*)d_in[19];

    float* out = (float*)d_out;
    float* ws  = (float*)d_ws;
    const size_t M1 = 1048576;           // 1M floats
    float* x1  = ws;                     // [0,1M)   x1 (live to end)
    float* adj = ws + M1;                // [1M,2M)  adj (live until dp gemm)
    float* hx  = ws + 2 * M1;            // [2M,3M)  h -> x2 -> delta -> yfull
    float* ax  = ws + 3 * M1;            // [3M,4M)  agg -> xc
    float* xr  = ws + 4 * M1;            // [4M,6M)  in_proj output (xm|res)
    float* dp  = ws + 6 * M1;            // [6M,7M)  delta_p
    float* bc  = ws + 7 * M1;            // [7M,7M+32K)  Bm,Cm per row
    unsigned long long* em = (unsigned long long*)(ws + 7 * M1 + 32768);

    const size_t gsm = (32 * 128 + 128 * 128) * sizeof(float);   // 80 KB
    const size_t asm_ = 128 * 128 * sizeof(float);               // 64 KB

    rms_k<<<BN_, 128, 0, stream>>>(x, norm_w, x1);
    copy_k<<<(BN_ * 3 + 255) / 256, 256, 0, stream>>>(pos, mi, out);
    adj_k<<<dim3(16, B_), 256, 0, stream>>>(pos, lin_w, lin_b, adj, em);
    // h = relu(x1 @ w1 + b1)
    gemm_k<1><<<dim3(256, 1), 256, gsm, stream>>>(x1, w1, b1, hx, nullptr, 128, 128, 0);
    // agg = (em @ h) / deg
    agg_k<<<dim3(4, B_), 256, asm_, stream>>>(hx, em, ax);
    // x2 = agg @ w2 + b2    (overwrites h slot)
    gemm_k<2><<<dim3(256, 1), 256, gsm, stream>>>(ax, w2, b2, hx, nullptr, 128, 128, 0);
    // xr = x2 @ in_proj  (8192 x 256)
    gemm_k<0><<<dim3(256, 2), 256, gsm, stream>>>(hx, in_proj, nullptr, xr, nullptr, 256, 256, 0);
    // conv + silu + x_proj + dt_proj + softplus  (xc -> ax, delta -> hx)
    convsm_k<<<BN_, 128, 0, stream>>>(xr, conv_w, conv_b, xpw, dtw, dtb, ax, bc, hx);
    // delta_p = delta @ adj[b]  (batched W)
    gemm_k<0><<<dim3(256, 1), 256, gsm, stream>>>(hx, adj, nullptr, dp, nullptr, 128, 128, N_ * N_);
    // scan -> yfull (into hx)
    scan_k<<<BN_ / 256, 256, 0, stream>>>(dp, ax, bc, xr, A_log, Dpar, hx);
    // out = clean(yfull @ out_proj) + x1   -> d_out
    gemm_k<3><<<dim3(256, 1), 256, gsm, stream>>>(hx, out_proj, nullptr, out, x1, 128, 128, 0);
}

// Round 2
// 138.570 us; speedup vs baseline: 1.3822x; 1.3822x over previous
//
#include <hip/hip_runtime.h>
#include <math.h>

// Problem constants
#define B_ 64
#define N_ 128
#define D_ 128
#define BN_ 8192            // B_*N_
#define NG_ 50
#define CUTOFF_ 10.0f

// ---------------------------------------------------------------------------
// 1. RMSNorm: x1[row][d] = x * rsqrt(mean(x^2)+eps) * w
// grid 8192 blocks x 128 threads
__global__ __launch_bounds__(128) void rms_k(const float* __restrict__ x,
                                             const float* __restrict__ w,
                                             float* __restrict__ x1) {
    int row = blockIdx.x;
    int d = threadIdx.x;
    float v = x[(size_t)row * D_ + d];
    float s = v * v;
    #pragma unroll
    for (int o = 32; o > 0; o >>= 1) s += __shfl_down(s, o, 64);
    __shared__ float acc2[2];
    if ((d & 63) == 0) acc2[d >> 6] = s;
    __syncthreads();
    float tot = acc2[0] + acc2[1];
    float r = rsqrtf(tot * (1.0f / D_) + 1e-5f);
    x1[(size_t)row * D_ + d] = v * r * w[d];
}

// ---------------------------------------------------------------------------
// 2. passthrough copy: pos (24576 floats) and map_idx (8192 ints -> float)
__global__ __launch_bounds__(256) void copy_k(const float* __restrict__ pos,
                                              const int* __restrict__ mi,
                                              float* __restrict__ out) {
    int i = blockIdx.x * 256 + threadIdx.x;
    if (i < BN_ * 3) out[(size_t)BN_ * D_ + i] = pos[i];
    if (i < BN_) out[(size_t)BN_ * D_ + BN_ * 3 + i] = (float)mi[i];
}

// ---------------------------------------------------------------------------
// 3. adjacency: dist, smeared adj, dense edge mask, 1/deg
// grid (16 row-tiles, 64 batches) x 256 threads; each block: 8 rows x 128 cols
__global__ __launch_bounds__(256) void adj_k(const float* __restrict__ pos,
                                             const float* __restrict__ lin_w,
                                             const float* __restrict__ lin_b,
                                             float* __restrict__ adj,
                                             float* __restrict__ emd,
                                             float* __restrict__ rdeg) {
    __shared__ float px[N_], py[N_], pz[N_];
    __shared__ float lw[NG_];
    __shared__ int degs[8];
    int b = blockIdx.y;
    int tid = threadIdx.x;
    if (tid < N_) {
        const float* p = pos + (size_t)(b * N_ + tid) * 3;
        px[tid] = p[0]; py[tid] = p[1]; pz[tid] = p[2];
    } else if (tid - N_ < NG_) {
        lw[tid - N_] = lin_w[tid - N_];
    }
    if (tid >= 248) degs[tid - 248] = 0;
    __syncthreads();
    float linb = lin_b[0];
    int j = tid & 127;
    int il = tid >> 7;          // 0..1
    const float DEL = 10.0f / 49.0f;
    const float COEFF = -0.5f / (DEL * DEL);
    #pragma unroll
    for (int p = 0; p < 4; p++) {
        int i = blockIdx.x * 8 + p * 2 + il;
        float dx = px[i] - px[j], dy = py[i] - py[j], dz = pz[i] - pz[j];
        float d2 = dx * dx + dy * dy + dz * dz;
        float dist = (i == j) ? 1.0f : sqrtf(d2);
        bool edge = (i != j) && (dist < CUTOFF_);
        float val = 0.0f;
        if (edge) {
            int g0 = (int)ceilf((dist - 1.75f) / DEL); if (g0 < 0) g0 = 0;
            int g1 = (int)floorf((dist + 1.75f) / DEL); if (g1 > NG_ - 1) g1 = NG_ - 1;
            float s = linb;
            for (int g = g0; g <= g1; g++) {
                float t = dist - (float)g * DEL;
                s += lw[g] * expf(COEFF * t * t);
            }
            val = s;
        }
        adj[((size_t)b * N_ + i) * N_ + j] = val;
        emd[((size_t)b * N_ + i) * N_ + j] = edge ? 1.0f : 0.0f;
        unsigned long long msk = __ballot(edge);
        if ((tid & 63) == 0) atomicAdd(&degs[p * 2 + il], __popcll(msk));
    }
    __syncthreads();
    if (tid < 8) {
        int dg = degs[tid];
        rdeg[(size_t)b * N_ + blockIdx.x * 8 + tid] = 1.0f / (float)(dg > 0 ? dg : 1);
    }
}

// ---------------------------------------------------------------------------
// Generic fp32 GEMM: C[M x ncols] = A[M x 128] @ W[128 x ncols] (+ epilogue)
// block tile 32 rows x 128 cols, thread tile 4x4, 256 threads.
// EPI: 0 = none, 1 = bias+relu, 2 = bias, 3 = isfinite-clean + add AUX (residual)
//      4 = scale by AUX[row] (rdeg)
// wbs: per-batch W stride (elements) for batched weight (0 = shared W)
template <int EPI>
__global__ __launch_bounds__(256) void gemm_k(const float* __restrict__ A,
                                              const float* __restrict__ W,
                                              const float* __restrict__ bias,
                                              float* __restrict__ C,
                                              const float* __restrict__ AUX,
                                              int wstride, int cstride, int wbs) {
    extern __shared__ float sm[];
    float* As = sm;              // 32*128
    float* Ws = sm + 32 * 128;   // 128*128
    int tid = threadIdx.x;
    int row_base = blockIdx.x * 32;
    int col_base = blockIdx.y * 128;

    // stage A tile (contiguous 4096 floats)
    const float4* Ag = reinterpret_cast<const float4*>(A + (size_t)row_base * 128);
    float4* As4 = reinterpret_cast<float4*>(As);
    #pragma unroll
    for (int i = 0; i < 4; i++) As4[tid + i * 256] = Ag[tid + i * 256];

    // stage W tile (128 rows x 128 cols)
    const float* Wp = W + (size_t)(row_base >> 7) * wbs;
    float4* Ws4 = reinterpret_cast<float4*>(Ws);
    #pragma unroll
    for (int i = 0; i < 16; i++) {
        int q = tid + i * 256;
        int r = q >> 5, cv = q & 31;
        Ws4[q] = *reinterpret_cast<const float4*>(Wp + (size_t)r * wstride + col_base + cv * 4);
    }
    __syncthreads();

    int ct = tid & 31, rt = tid >> 5;
    int c0 = ct * 4, r0 = rt * 4;
    float acc[4][4] = {};
    #pragma unroll 4
    for (int kb = 0; kb < 32; kb++) {
        float af[4][4], wf[4][4];
        #pragma unroll
        for (int i = 0; i < 4; i++) {
            float4 t = As4[(r0 + i) * 32 + kb];
            af[i][0] = t.x; af[i][1] = t.y; af[i][2] = t.z; af[i][3] = t.w;
        }
        #pragma unroll
        for (int kk = 0; kk < 4; kk++) {
            float4 t = Ws4[(kb * 4 + kk) * 32 + ct];
            wf[kk][0] = t.x; wf[kk][1] = t.y; wf[kk][2] = t.z; wf[kk][3] = t.w;
        }
        #pragma unroll
        for (int kk = 0; kk < 4; kk++)
            #pragma unroll
            for (int i = 0; i < 4; i++)
                #pragma unroll
                for (int jj = 0; jj < 4; jj++)
                    acc[i][jj] = fmaf(af[i][kk], wf[kk][jj], acc[i][jj]);
    }

    #pragma unroll
    for (int i = 0; i < 4; i++) {
        int row = row_base + r0 + i;
        int col = col_base + c0;
        float v[4];
        #pragma unroll
        for (int jj = 0; jj < 4; jj++) {
            float t = acc[i][jj];
            if (EPI == 1) { t += bias[col + jj]; t = fmaxf(t, 0.0f); }
            if (EPI == 2) { t += bias[col + jj]; }
            if (EPI == 3) {
                t = isfinite(t) ? t : 0.0f;
                t += AUX[(size_t)row * 128 + col + jj];
            }
            if (EPI == 4) { t *= AUX[row]; }
            v[jj] = t;
        }
        float4 o = make_float4(v[0], v[1], v[2], v[3]);
        *reinterpret_cast<float4*>(C + (size_t)row * cstride + col) = o;
    }
}

// ---------------------------------------------------------------------------
// 8. fused conv1d + silu + x_proj + dt_proj + softplus, per (b,t) row
// grid 8192 x 128 threads (thread = channel d)
__global__ __launch_bounds__(128) void convsm_k(const float* __restrict__ xr,
                                                const float* __restrict__ conv_w,
                                                const float* __restrict__ conv_b,
                                                const float* __restrict__ xpw,
                                                const float* __restrict__ dtw,
                                                const float* __restrict__ dtb,
                                                float* __restrict__ xc,
                                                float* __restrict__ bc,
                                                float* __restrict__ delta) {
    int row = blockIdx.x;
    int bt = row & 127;
    int d = threadIdx.x;
    float accv = conv_b[d];
    #pragma unroll
    for (int jj = 0; jj < 4; jj++) {
        int tt = bt + jj - 3;
        if (tt >= 0) accv = fmaf(xr[((size_t)(row + jj - 3)) * 256 + d], conv_w[d * 4 + jj], accv);
    }
    float xcv = accv / (1.0f + expf(-accv));   // silu
    xc[(size_t)row * D_ + d] = xcv;
    __shared__ float xs[D_];
    __shared__ float dbl[12];
    xs[d] = xcv;
    __syncthreads();
    if (d < 12) {
        float s = 0.0f;
        for (int k = 0; k < D_; k++) s = fmaf(xs[k], xpw[k * 12 + d], s);
        dbl[d] = s;
        if (d >= 8) bc[(size_t)row * 4 + (d - 8)] = s;
    }
    __syncthreads();
    float s = dtb[d];
    #pragma unroll
    for (int r = 0; r < 8; r++) s = fmaf(dbl[r], dtw[r * D_ + d], s);
    float sp = fmaxf(s, 0.0f) + log1pf(expf(-fabsf(s)));  // softplus
    delta[(size_t)row * D_ + d] = sp;
}

// ---------------------------------------------------------------------------
// 10. selective scan: one thread per (b,d), sequential over t=0..127
// yfull = (y + xc*D_param) * silu(res)
__global__ __launch_bounds__(256) void scan_k(const float* __restrict__ dp_,
                                              const float* __restrict__ xc,
                                              const float* __restrict__ bc,
                                              const float* __restrict__ xr,
                                              const float* __restrict__ A_log,
                                              const float* __restrict__ Dpar,
                                              float* __restrict__ yfull) {
    int g = blockIdx.x * 256 + threadIdx.x;
    int b = g >> 7, d = g & 127;
    float a1 = -expf(A_log[d * 2]);
    float a2 = -expf(A_log[d * 2 + 1]);
    float Dp = Dpar[d];
    float h1 = 0.0f, h2 = 0.0f;
    size_t base = (size_t)b * N_;
    for (int t = 0; t < N_; t++) {
        size_t row = base + t;
        float dpv = dp_[row * D_ + d];
        float xcv = xc[row * D_ + d];
        float bm0 = bc[row * 4 + 0], bm1 = bc[row * 4 + 1];
        float cm0 = bc[row * 4 + 2], cm1 = bc[row * 4 + 3];
        float e1 = expf(dpv * a1), e2 = expf(dpv * a2);
        float bu = dpv * xcv;
        h1 = fmaf(e1, h1, bu * bm0);
        h2 = fmaf(e2, h2, bu * bm1);
        float y = fmaf(h1, cm0, h2 * cm1);
        float r = xr[row * 256 + 128 + d];
        float yv = fmaf(xcv, Dp, y) * (r / (1.0f + expf(-r)));
        yfull[row * D_ + d] = yv;
    }
}

// ---------------------------------------------------------------------------
extern "C" void kernel_launch(void* const* d_in, const int* in_sizes, int n_in,
                              void* d_out, int out_size, void* d_ws, size_t ws_size,
                              hipStream_t stream) {
    const float* x        = (const float*)d_in[0];
    const float* pos      = (const float*)d_in[1];
    const int*   mi       = (const int*)d_in[2];
    // d_in[3] = batch (unused)
    const float* norm_w   = (const float*)d_in[4];
    const float* w1       = (const float*)d_in[5];
    const float* b1       = (const float*)d_in[6];
    const float* w2       = (const float*)d_in[7];
    const float* b2       = (const float*)d_in[8];
    const float* lin_w    = (const float*)d_in[9];
    const float* lin_b    = (const float*)d_in[10];
    const float* in_proj  = (const float*)d_in[11];
    const float* conv_w   = (const float*)d_in[12];
    const float* conv_b   = (const float*)d_in[13];
    const float* xpw      = (const float*)d_in[14];
    const float* dtw      = (const float*)d_in[15];
    const float* dtb      = (const float*)d_in[16];
    const float* A_log    = (const float*)d_in[17];
    const float* Dpar     = (const float*)d_in[18];
    const float* out_proj = (const float*)d_in[19];

    float* out = (float*)d_out;
    float* ws  = (float*)d_ws;
    const size_t M1 = 1048576;           // 1M floats
    float* x1  = ws;                     // [0,1M)   x1 (live to end)
    float* adj = ws + M1;                // [1M,2M)  adj (live until dp gemm)
    float* hx  = ws + 2 * M1;            // [2M,3M)  h -> x2 -> delta -> yfull
    float* ax  = ws + 3 * M1;            // [3M,4M)  agg -> xc
    float* xr  = ws + 4 * M1;            // [4M,6M)  in_proj output (xm|res)
    float* dp  = ws + 6 * M1;            // [6M,7M)  em_dense -> delta_p
    float* bc  = ws + 7 * M1;            // [7M,7M+32K)  Bm,Cm per row
    float* rdeg = ws + 7 * M1 + 32768;   // 8192 floats

    const size_t gsm = (32 * 128 + 128 * 128) * sizeof(float);   // 80 KB

    rms_k<<<BN_, 128, 0, stream>>>(x, norm_w, x1);
    copy_k<<<(BN_ * 3 + 255) / 256, 256, 0, stream>>>(pos, mi, out);
    adj_k<<<dim3(16, B_), 256, 0, stream>>>(pos, lin_w, lin_b, adj, dp, rdeg);
    // h = relu(x1 @ w1 + b1)
    gemm_k<1><<<dim3(256, 1), 256, gsm, stream>>>(x1, w1, b1, hx, nullptr, 128, 128, 0);
    // agg = (em_dense @ h) * rdeg   (batched W = h[b], em_dense lives in dp slot)
    gemm_k<4><<<dim3(256, 1), 256, gsm, stream>>>(dp, hx, nullptr, ax, rdeg, 128, 128, N_ * N_);
    // x2 = agg @ w2 + b2    (overwrites h slot)
    gemm_k<2><<<dim3(256, 1), 256, gsm, stream>>>(ax, w2, b2, hx, nullptr, 128, 128, 0);
    // xr = x2 @ in_proj  (8192 x 256)
    gemm_k<0><<<dim3(256, 2), 256, gsm, stream>>>(hx, in_proj, nullptr, xr, nullptr, 256, 256, 0);
    // conv + silu + x_proj + dt_proj + softplus  (xc -> ax, delta -> hx)
    convsm_k<<<BN_, 128, 0, stream>>>(xr, conv_w, conv_b, xpw, dtw, dtb, ax, bc, hx);
    // delta_p = delta @ adj[b]  (batched W; overwrites em_dense slot)
    gemm_k<0><<<dim3(256, 1), 256, gsm, stream>>>(hx, adj, nullptr, dp, nullptr, 128, 128, N_ * N_);
    // scan -> yfull (into hx)
    scan_k<<<BN_ / 256, 256, 0, stream>>>(dp, ax, bc, xr, A_log, Dpar, hx);
    // out = clean(yfull @ out_proj) + x1   -> d_out
    gemm_k<3><<<dim3(256, 1), 256, gsm, stream>>>(hx, out_proj, nullptr, out, x1, 128, 128, 0);
}

// Round 3
// 136.935 us; speedup vs baseline: 1.3987x; 1.0119x over previous
//
#include <hip/hip_runtime.h>
#include <math.h>

// Problem constants
#define B_ 64
#define N_ 128
#define D_ 128
#define BN_ 8192            // B_*N_
#define NG_ 50
#define CUTOFF_ 10.0f

// ---------------------------------------------------------------------------
// async global->LDS helper (16B per lane, wave-uniform LDS base + lane*16)
__device__ __forceinline__ void gl_lds16(const float* g, float* l) {
    __builtin_amdgcn_global_load_lds(
        (const __attribute__((address_space(1))) void*)(g),
        (__attribute__((address_space(3))) void*)(l), 16, 0, 0);
}

// ---------------------------------------------------------------------------
// 0. weight-fusion prep: Wf = w2 @ in_proj (128x256), bf = b2 @ in_proj (256),
//    Wd = xpw[:, :8] @ dtw (128x128)
__global__ __launch_bounds__(256) void fuse_k(const float* __restrict__ w2,
                                              const float* __restrict__ in_proj,
                                              const float* __restrict__ b2,
                                              const float* __restrict__ xpw,
                                              const float* __restrict__ dtw,
                                              float* __restrict__ Wf,
                                              float* __restrict__ bf,
                                              float* __restrict__ Wd) {
    int blk = blockIdx.x, t = threadIdx.x;
    if (blk < 128) {
        float s = 0.0f;
        #pragma unroll 8
        for (int k = 0; k < 128; k++) s = fmaf(w2[blk * 128 + k], in_proj[k * 256 + t], s);
        Wf[blk * 256 + t] = s;
    } else if (blk < 256) {
        int m = blk - 128;
        if (t < 128) {
            float s = 0.0f;
            #pragma unroll
            for (int r = 0; r < 8; r++) s = fmaf(xpw[m * 12 + r], dtw[r * 128 + t], s);
            Wd[m * 128 + t] = s;
        }
    } else {
        float s = 0.0f;
        #pragma unroll 8
        for (int k = 0; k < 128; k++) s = fmaf(b2[k], in_proj[k * 256 + t], s);
        bf[t] = s;
    }
}

// ---------------------------------------------------------------------------
// 1. RMSNorm
__global__ __launch_bounds__(128) void rms_k(const float* __restrict__ x,
                                             const float* __restrict__ w,
                                             float* __restrict__ x1) {
    int row = blockIdx.x;
    int d = threadIdx.x;
    float v = x[(size_t)row * D_ + d];
    float s = v * v;
    #pragma unroll
    for (int o = 32; o > 0; o >>= 1) s += __shfl_down(s, o, 64);
    __shared__ float acc2[2];
    if ((d & 63) == 0) acc2[d >> 6] = s;
    __syncthreads();
    float tot = acc2[0] + acc2[1];
    float r = rsqrtf(tot * (1.0f / D_) + 1e-5f);
    x1[(size_t)row * D_ + d] = v * r * w[d];
}

// ---------------------------------------------------------------------------
// 2. passthrough copy
__global__ __launch_bounds__(256) void copy_k(const float* __restrict__ pos,
                                              const int* __restrict__ mi,
                                              float* __restrict__ out) {
    int i = blockIdx.x * 256 + threadIdx.x;
    if (i < BN_ * 3) out[(size_t)BN_ * D_ + i] = pos[i];
    if (i < BN_) out[(size_t)BN_ * D_ + BN_ * 3 + i] = (float)mi[i];
}

// ---------------------------------------------------------------------------
// 3. adjacency: smeared adj, dense edge mask, 1/deg
__global__ __launch_bounds__(256) void adj_k(const float* __restrict__ pos,
                                             const float* __restrict__ lin_w,
                                             const float* __restrict__ lin_b,
                                             float* __restrict__ adj,
                                             float* __restrict__ emd,
                                             float* __restrict__ rdeg) {
    __shared__ float px[N_], py[N_], pz[N_];
    __shared__ float lw[NG_];
    __shared__ int degs[8];
    int b = blockIdx.y;
    int tid = threadIdx.x;
    if (tid < N_) {
        const float* p = pos + (size_t)(b * N_ + tid) * 3;
        px[tid] = p[0]; py[tid] = p[1]; pz[tid] = p[2];
    } else if (tid - N_ < NG_) {
        lw[tid - N_] = lin_w[tid - N_];
    }
    if (tid >= 248) degs[tid - 248] = 0;
    __syncthreads();
    float linb = lin_b[0];
    int j = tid & 127;
    int il = tid >> 7;
    const float DEL = 10.0f / 49.0f;
    const float COEFF = -0.5f / (DEL * DEL);
    #pragma unroll
    for (int p = 0; p < 4; p++) {
        int i = blockIdx.x * 8 + p * 2 + il;
        float dx = px[i] - px[j], dy = py[i] - py[j], dz = pz[i] - pz[j];
        float d2 = dx * dx + dy * dy + dz * dz;
        float dist = (i == j) ? 1.0f : sqrtf(d2);
        bool edge = (i != j) && (dist < CUTOFF_);
        float val = 0.0f;
        if (edge) {
            int g0 = (int)ceilf((dist - 1.75f) / DEL); if (g0 < 0) g0 = 0;
            int g1 = (int)floorf((dist + 1.75f) / DEL); if (g1 > NG_ - 1) g1 = NG_ - 1;
            float s = linb;
            for (int g = g0; g <= g1; g++) {
                float t = dist - (float)g * DEL;
                s += lw[g] * expf(COEFF * t * t);
            }
            val = s;
        }
        adj[((size_t)b * N_ + i) * N_ + j] = val;
        emd[((size_t)b * N_ + i) * N_ + j] = edge ? 1.0f : 0.0f;
        unsigned long long msk = __ballot(edge);
        if ((tid & 63) == 0) atomicAdd(&degs[p * 2 + il], __popcll(msk));
    }
    __syncthreads();
    if (tid < 8) {
        int dg = degs[tid];
        rdeg[(size_t)b * N_ + blockIdx.x * 8 + tid] = 1.0f / (float)(dg > 0 ? dg : 1);
    }
}

// ---------------------------------------------------------------------------
// Generic fp32 GEMM: C[M x ncols] = A[M x 128] @ W[128 x ncols] (+ epilogue)
// block tile 16 rows x 128 cols, thread tile 2x4, 256 threads, 72KB LDS
// (2 blocks/CU). A and W staged via global_load_lds (async DMA).
// EPI: 0 none, 1 bias+relu, 2 bias, 3 isfinite-clean + add AUX, 4 scale AUX[row],
//      5 softplus(t + bias)
// wbs: per-batch W stride (0 = shared W)
template <int EPI>
__global__ __launch_bounds__(256, 2) void gemm_k(const float* __restrict__ A,
                                                 const float* __restrict__ W,
                                                 const float* __restrict__ bias,
                                                 float* __restrict__ C,
                                                 const float* __restrict__ AUX,
                                                 int wstride, int cstride, int wbs) {
    extern __shared__ float sm[];
    float* As = sm;              // 16*128
    float* Ws = sm + 16 * 128;   // 128*128
    int tid = threadIdx.x;
    int row_base = blockIdx.x * 16;
    int col_base = blockIdx.y * 128;

    float4* As4 = reinterpret_cast<float4*>(As);
    float4* Ws4 = reinterpret_cast<float4*>(Ws);

    // stage A tile (16x128 = 512 float4) via async DMA
    const float* Ag = A + (size_t)row_base * 128;
    #pragma unroll
    for (int i = 0; i < 2; i++) {
        int q = tid + i * 256;
        gl_lds16(Ag + q * 4, (float*)(As4 + q));
    }
    // stage W tile (128 x 128 cols = 4096 float4)
    const float* Wp = W + (size_t)(row_base >> 7) * wbs;
    #pragma unroll
    for (int i = 0; i < 16; i++) {
        int q = tid + i * 256;
        int r = q >> 5, cv = q & 31;
        gl_lds16(Wp + (size_t)r * wstride + col_base + cv * 4, (float*)(Ws4 + q));
    }
    __syncthreads();   // drains vmcnt for the async LDS loads

    int ct = tid & 31, rt = tid >> 5;
    int c0 = ct * 4, r0 = rt * 2;
    float acc[2][4] = {};
    #pragma unroll 4
    for (int kb = 0; kb < 32; kb++) {
        float af[2][4], wf[4][4];
        #pragma unroll
        for (int i = 0; i < 2; i++) {
            float4 t = As4[(r0 + i) * 32 + kb];
            af[i][0] = t.x; af[i][1] = t.y; af[i][2] = t.z; af[i][3] = t.w;
        }
        #pragma unroll
        for (int kk = 0; kk < 4; kk++) {
            float4 t = Ws4[(kb * 4 + kk) * 32 + ct];
            wf[kk][0] = t.x; wf[kk][1] = t.y; wf[kk][2] = t.z; wf[kk][3] = t.w;
        }
        #pragma unroll
        for (int kk = 0; kk < 4; kk++)
            #pragma unroll
            for (int i = 0; i < 2; i++)
                #pragma unroll
                for (int jj = 0; jj < 4; jj++)
                    acc[i][jj] = fmaf(af[i][kk], wf[kk][jj], acc[i][jj]);
    }

    #pragma unroll
    for (int i = 0; i < 2; i++) {
        int row = row_base + r0 + i;
        int col = col_base + c0;
        float v[4];
        #pragma unroll
        for (int jj = 0; jj < 4; jj++) {
            float t = acc[i][jj];
            if (EPI == 1) { t += bias[col + jj]; t = fmaxf(t, 0.0f); }
            if (EPI == 2) { t += bias[col + jj]; }
            if (EPI == 3) {
                t = isfinite(t) ? t : 0.0f;
                t += AUX[(size_t)row * 128 + col + jj];
            }
            if (EPI == 4) { t *= AUX[row]; }
            if (EPI == 5) {
                t += bias[col + jj];
                t = fmaxf(t, 0.0f) + log1pf(expf(-fabsf(t)));   // softplus
            }
            v[jj] = t;
        }
        float4 o = make_float4(v[0], v[1], v[2], v[3]);
        *reinterpret_cast<float4*>(C + (size_t)row * cstride + col) = o;
    }
}

// ---------------------------------------------------------------------------
// 8. conv1d + silu -> xc ; bc = xc @ xpw[:, 8:12] (wave-shuffle reduction)
__global__ __launch_bounds__(128) void convsm_k(const float* __restrict__ xr,
                                                const float* __restrict__ conv_w,
                                                const float* __restrict__ conv_b,
                                                const float* __restrict__ xpw,
                                                float* __restrict__ xc,
                                                float* __restrict__ bc) {
    int row = blockIdx.x;
    int bt = row & 127;
    int d = threadIdx.x;
    float accv = conv_b[d];
    #pragma unroll
    for (int jj = 0; jj < 4; jj++) {
        int tt = bt + jj - 3;
        if (tt >= 0) accv = fmaf(xr[((size_t)(row + jj - 3)) * 256 + d], conv_w[d * 4 + jj], accv);
    }
    float xcv = accv / (1.0f + expf(-accv));   // silu
    xc[(size_t)row * D_ + d] = xcv;
    float4 wv = *reinterpret_cast<const float4*>(xpw + d * 12 + 8);
    float p0 = xcv * wv.x, p1 = xcv * wv.y, p2 = xcv * wv.z, p3 = xcv * wv.w;
    #pragma unroll
    for (int o = 32; o > 0; o >>= 1) {
        p0 += __shfl_down(p0, o, 64);
        p1 += __shfl_down(p1, o, 64);
        p2 += __shfl_down(p2, o, 64);
        p3 += __shfl_down(p3, o, 64);
    }
    __shared__ float red[2][4];
    if ((d & 63) == 0) {
        int w = d >> 6;
        red[w][0] = p0; red[w][1] = p1; red[w][2] = p2; red[w][3] = p3;
    }
    __syncthreads();
    if (d < 4) bc[(size_t)row * 4 + d] = red[0][d] + red[1][d];
}

// ---------------------------------------------------------------------------
// 10. selective scan
__global__ __launch_bounds__(256) void scan_k(const float* __restrict__ dp_,
                                              const float* __restrict__ xc,
                                              const float* __restrict__ bc,
                                              const float* __restrict__ xr,
                                              const float* __restrict__ A_log,
                                              const float* __restrict__ Dpar,
                                              float* __restrict__ yfull) {
    int g = blockIdx.x * 256 + threadIdx.x;
    int b = g >> 7, d = g & 127;
    float a1 = -expf(A_log[d * 2]);
    float a2 = -expf(A_log[d * 2 + 1]);
    float Dp = Dpar[d];
    float h1 = 0.0f, h2 = 0.0f;
    size_t base = (size_t)b * N_;
    for (int t = 0; t < N_; t++) {
        size_t row = base + t;
        float dpv = dp_[row * D_ + d];
        float xcv = xc[row * D_ + d];
        float bm0 = bc[row * 4 + 0], bm1 = bc[row * 4 + 1];
        float cm0 = bc[row * 4 + 2], cm1 = bc[row * 4 + 3];
        float e1 = expf(dpv * a1), e2 = expf(dpv * a2);
        float bu = dpv * xcv;
        h1 = fmaf(e1, h1, bu * bm0);
        h2 = fmaf(e2, h2, bu * bm1);
        float y = fmaf(h1, cm0, h2 * cm1);
        float r = xr[row * 256 + 128 + d];
        float yv = fmaf(xcv, Dp, y) * (r / (1.0f + expf(-r)));
        yfull[row * D_ + d] = yv;
    }
}

// ---------------------------------------------------------------------------
extern "C" void kernel_launch(void* const* d_in, const int* in_sizes, int n_in,
                              void* d_out, int out_size, void* d_ws, size_t ws_size,
                              hipStream_t stream) {
    const float* x        = (const float*)d_in[0];
    const float* pos      = (const float*)d_in[1];
    const int*   mi       = (const int*)d_in[2];
    const float* norm_w   = (const float*)d_in[4];
    const float* w1       = (const float*)d_in[5];
    const float* b1       = (const float*)d_in[6];
    const float* w2       = (const float*)d_in[7];
    const float* b2       = (const float*)d_in[8];
    const float* lin_w    = (const float*)d_in[9];
    const float* lin_b    = (const float*)d_in[10];
    const float* in_proj  = (const float*)d_in[11];
    const float* conv_w   = (const float*)d_in[12];
    const float* conv_b   = (const float*)d_in[13];
    const float* xpw      = (const float*)d_in[14];
    const float* dtw      = (const float*)d_in[15];
    const float* dtb      = (const float*)d_in[16];
    const float* A_log    = (const float*)d_in[17];
    const float* Dpar     = (const float*)d_in[18];
    const float* out_proj = (const float*)d_in[19];

    float* out = (float*)d_out;
    float* ws  = (float*)d_ws;
    const size_t M1 = 1048576;           // 1M floats
    float* x1  = ws;                     // x1 (live to end)
    float* adj = ws + M1;                // adj
    float* hx  = ws + 2 * M1;            // h -> delta -> yfull
    float* ax  = ws + 3 * M1;            // agg -> xc
    float* xr  = ws + 4 * M1;            // in_proj output (xm|res), 2M
    float* dp  = ws + 6 * M1;            // em_dense -> delta_p
    float* bc  = ws + 7 * M1;            // 32K floats
    float* rdeg = ws + 7 * M1 + 32768;   // 8192
    float* Wf  = ws + 7 * M1 + 65536;    // 128*256
    float* bf  = Wf + 32768;             // 256
    float* Wd  = bf + 256;               // 128*128

    const size_t gsm = (16 * 128 + 128 * 128) * sizeof(float);   // 72 KB

    fuse_k<<<257, 256, 0, stream>>>(w2, in_proj, b2, xpw, dtw, Wf, bf, Wd);
    rms_k<<<BN_, 128, 0, stream>>>(x, norm_w, x1);
    copy_k<<<(BN_ * 3 + 255) / 256, 256, 0, stream>>>(pos, mi, out);
    adj_k<<<dim3(16, B_), 256, 0, stream>>>(pos, lin_w, lin_b, adj, dp, rdeg);
    // h = relu(x1 @ w1 + b1)
    gemm_k<1><<<dim3(512, 1), 256, gsm, stream>>>(x1, w1, b1, hx, nullptr, 128, 128, 0);
    // agg = (em_dense @ h[b]) * rdeg
    gemm_k<4><<<dim3(512, 1), 256, gsm, stream>>>(dp, hx, nullptr, ax, rdeg, 128, 128, N_ * N_);
    // xr = agg @ Wf + bf   (fused w2+in_proj)
    gemm_k<2><<<dim3(512, 2), 256, gsm, stream>>>(ax, Wf, bf, xr, nullptr, 256, 256, 0);
    // conv + silu -> xc(ax);  bc side output
    convsm_k<<<BN_, 128, 0, stream>>>(xr, conv_w, conv_b, xpw, ax, bc);
    // delta = softplus(xc @ Wd + dtb)
    gemm_k<5><<<dim3(512, 1), 256, gsm, stream>>>(ax, Wd, dtb, hx, nullptr, 128, 128, 0);
    // delta_p = delta @ adj[b]
    gemm_k<0><<<dim3(512, 1), 256, gsm, stream>>>(hx, adj, nullptr, dp, nullptr, 128, 128, N_ * N_);
    // scan -> yfull
    scan_k<<<BN_ / 256, 256, 0, stream>>>(dp, ax, bc, xr, A_log, Dpar, hx);
    // out = clean(yfull @ out_proj) + x1
    gemm_k<3><<<dim3(512, 1), 256, gsm, stream>>>(hx, out_proj, nullptr, out, x1, 128, 128, 0);
}